// Round 5
// baseline (643.850 us; speedup 1.0000x reference)
//
#include <hip/hip_runtime.h>
#include <stdint.h>

#define H_ 16
#define DH_ 128
#define RK_ 512
#define RD_ 64
#define B_ 2
#define L_ 2048
#define E_ 2048
#define DQ_ 192            // DH+RD
#define NQ_ (H_*DQ_)       // 3072
#define NKV_ 576
#define NKVP_ 640
#define NUP_ (H_*(2*DH_+RD_)) // 5120
#define M_ (B_*L_)         // 4096

typedef unsigned short u16;
typedef __bf16 bf16x8 __attribute__((ext_vector_type(8)));
typedef float floatx4 __attribute__((ext_vector_type(4)));

__device__ __forceinline__ u16 f2bf(float f) {
    union { float f; uint32_t u; } v; v.f = f;
    uint32_t u = v.u;
    u = (u + 0x7fffu + ((u >> 16) & 1u)) >> 16;
    return (u16)u;
}
__device__ __forceinline__ float bf2f(u16 b) {
    union { uint32_t u; float f; } v; v.u = ((uint32_t)b) << 16; return v.f;
}

__device__ __forceinline__ void gld_lds16(const void* g, void* l) {
    __builtin_amdgcn_global_load_lds((__attribute__((address_space(1))) void*)(g),
                                     (__attribute__((address_space(3))) void*)(l),
                                     16, 0, 0);
}

// ---------------- fp32 -> bf16 elementwise (x) ----------------
__global__ void convert_bf16(const float* __restrict__ in, u16* __restrict__ out, int n4) {
    int i = blockIdx.x * blockDim.x + threadIdx.x;
    if (i >= n4) return;
    float4 v = ((const float4*)in)[i];
    uint2 o;
    o.x = (uint32_t)f2bf(v.x) | ((uint32_t)f2bf(v.y) << 16);
    o.y = (uint32_t)f2bf(v.z) | ((uint32_t)f2bf(v.w) << 16);
    ((uint2*)out)[i] = o;
}

// ---------------- W (KxN fp32) -> Wt (Npad x K bf16), zero pad ----------------
__global__ void transpose_w(const float* __restrict__ W, u16* __restrict__ Wt,
                            int K, int N, int Npad) {
    __shared__ float tile[32][33];
    int n0 = blockIdx.x * 32, k0 = blockIdx.y * 32;
    int tx = threadIdx.x, ty = threadIdx.y; // 32 x 8
    for (int i = 0; i < 4; i++) {
        int k = k0 + ty + i * 8, n = n0 + tx;
        tile[ty + i * 8][tx] = (n < N) ? W[(size_t)k * N + n] : 0.f;
    }
    __syncthreads();
    for (int i = 0; i < 4; i++) {
        int n = n0 + ty + i * 8, k = k0 + tx;
        Wt[(size_t)n * K + k] = f2bf(tile[tx][ty + i * 8]);
    }
}

// ---------------- GEMM: C(MxN fp32) = A(MxK bf16) * Bt(NxK bf16)^T ----------------
__global__ __launch_bounds__(256) void gemm_bt(const u16* __restrict__ A,
                                               const u16* __restrict__ Bt,
                                               float* __restrict__ C,
                                               int M, int N, int K) {
    __shared__ __align__(16) u16 As[128 * 32];
    __shared__ __align__(16) u16 Bs[128 * 32];
    const int tid = threadIdx.x;
    const int wave = tid >> 6, lane = tid & 63;
    const int quad = lane >> 4, l16 = lane & 15;
    const int m0 = blockIdx.y * 128, n0 = blockIdx.x * 128;
    const int wm = (wave >> 1) * 64, wn = (wave & 1) * 64;

    floatx4 zero4 = {0.f, 0.f, 0.f, 0.f};
    floatx4 acc[4][4];
    for (int i = 0; i < 4; i++) for (int j = 0; j < 4; j++) acc[i][j] = zero4;

    const u16* Ab = A + (size_t)m0 * K;
    const u16* Bb = Bt + (size_t)n0 * K;

    for (int k0 = 0; k0 < K; k0 += 32) {
        for (int it = 0; it < 2; ++it) {
            int c = it * 256 + tid;
            int row = c >> 2, cr = c & 3;
            gld_lds16(Ab + (size_t)row * K + k0 + cr * 8, As + c * 8);
            gld_lds16(Bb + (size_t)row * K + k0 + cr * 8, Bs + c * 8);
        }
        __syncthreads();
        bf16x8 af[4], bfr[4];
        for (int i = 0; i < 4; i++) af[i]  = *(const bf16x8*)(As + (wm + i * 16 + l16) * 32 + quad * 8);
        for (int j = 0; j < 4; j++) bfr[j] = *(const bf16x8*)(Bs + (wn + j * 16 + l16) * 32 + quad * 8);
        for (int i = 0; i < 4; i++)
            for (int j = 0; j < 4; j++)
                acc[i][j] = __builtin_amdgcn_mfma_f32_16x16x32_bf16(af[i], bfr[j], acc[i][j], 0, 0, 0);
        __syncthreads();
    }
    for (int i = 0; i < 4; i++)
        for (int j = 0; j < 4; j++) {
            int mrow = m0 + wm + i * 16 + quad * 4;
            int ncol = n0 + wn + j * 16 + l16;
            float* Cp = C + (size_t)mrow * N + ncol;
            for (int r = 0; r < 4; r++) Cp[(size_t)r * N] = acc[i][j][r];
        }
}

// ---------------- build q: rope + scale*log2e + layout (B,H,L,192) bf16 ----------------
__global__ void build_q(const float* __restrict__ q_all, const float* __restrict__ cosT,
                        const float* __restrict__ sinT, u16* __restrict__ qb) {
    const float QS = 0.07216878364870323f * 1.4426950408889634f; // 1/sqrt(192) * log2(e)
    int idx = blockIdx.x * blockDim.x + threadIdx.x;
    if (idx >= M_ * H_ * 96) return;
    int p = idx % 96; int t = idx / 96; int h = t % H_; int row = t / H_;
    int l = row & (L_ - 1); int b = row >> 11;
    const float* src = q_all + (size_t)row * NQ_ + h * DQ_;
    u16* dst = qb + ((size_t)(b * H_ + h) * L_ + l) * DQ_;
    int d = 2 * p;
    float x1 = src[d], x2 = src[d + 1];
    if (d < DH_) { dst[d] = f2bf(x1 * QS); dst[d + 1] = f2bf(x2 * QS); }
    else {
        int i = (d - DH_) >> 1;
        float c = cosT[(size_t)l * 32 + i], s = sinT[(size_t)l * 32 + i];
        dst[d]     = f2bf((x1 * c - x2 * s) * QS);
        dst[d + 1] = f2bf((x1 * s + x2 * c) * QS);
    }
}

// ---------------- build c_kv (bf16) + roped k_rope (bf16) ----------------
__global__ void build_ckv(const float* __restrict__ kv, const float* __restrict__ cosT,
                          const float* __restrict__ sinT, u16* __restrict__ ckv,
                          u16* __restrict__ kropeb) {
    int idx = blockIdx.x * blockDim.x + threadIdx.x;
    if (idx >= M_ * 288) return;
    int j = idx % 288; int row = idx / 288;
    int l = row & (L_ - 1);
    const float* src = kv + (size_t)row * NKVP_;
    if (j < 256) {
        ckv[(size_t)row * RK_ + 2 * j]     = f2bf(src[2 * j]);
        ckv[(size_t)row * RK_ + 2 * j + 1] = f2bf(src[2 * j + 1]);
    } else {
        int i = j - 256;
        float x1 = src[RK_ + 2 * i], x2 = src[RK_ + 2 * i + 1];
        float c = cosT[(size_t)l * 32 + i], s = sinT[(size_t)l * 32 + i];
        kropeb[(size_t)row * RD_ + 2 * i]     = f2bf(x1 * c - x2 * s);
        kropeb[(size_t)row * RD_ + 2 * i + 1] = f2bf(x1 * s + x2 * c);
    }
}

// ---------------- build k (B,H,L,192) + vT (B,H,192,L perm) bf16 ----------------
// vtb stores s-index permuted within each 32-group: k = ((s>>2)&3)*8 + ((s>>4)&1)*4 + (s&3)
// so the PV MFMA's B-frag element (k=quad*8+j) matches the S^T C-layout rows.
__global__ __launch_bounds__(256) void build_kvt(const float* __restrict__ up,
        const u16* __restrict__ kropeb, u16* __restrict__ kb, u16* __restrict__ vtb) {
    __shared__ float vt[64][193];
    int blk = blockIdx.x;          // (b*H+h)*32 + lt
    int lt = blk & 31; int bh = blk >> 5; int h = bh % H_; int b = bh / H_;
    int tid = threadIdx.x;
    int l0 = lt * 64;
    for (int it = 0; it < 48; ++it) {
        int idx = it * 256 + tid;  // 64*192
        int lr = idx / 192, d = idx % 192;
        size_t row = (size_t)b * L_ + l0 + lr;
        float vv = (d < DH_) ? up[row * NUP_ + h * 320 + DH_ + d]
                             : up[row * NUP_ + h * 320 + 2 * DH_ + (d - DH_)];
        vt[lr][d] = vv;
        u16 kbf = (d < DH_) ? f2bf(up[row * NUP_ + h * 320 + d])
                            : kropeb[row * RD_ + (d - DH_)];
        kb[((size_t)bh * L_ + l0 + lr) * DQ_ + d] = kbf;
    }
    __syncthreads();
    for (int it = 0; it < 48; ++it) {
        int idx = it * 256 + tid;
        int lr = idx & 63, d = idx >> 6;
        int l = l0 + lr;
        int s5 = l & 31;
        int k5 = ((s5 >> 2) & 3) * 8 + ((s5 >> 4) & 1) * 4 + (s5 & 3);
        int lp = (l & ~31) | k5;
        vtb[((size_t)bh * DQ_ + d) * L_ + lp] = f2bf(vt[lr][d]);
    }
}

// ---------------- flash attention, causal, S^T, split-s QUARTERS ----------------
// Grid = 512 blocks (2 per CU by LDS: 48KB*2=96KB<=160KB). Block (bh,t,j):
// quarter-j of supertile QT=7-t then quarter-j of QT=t -> exactly 9 st-iters
// per block. Two independent blocks/CU overlap each other's barrier stalls.
// Quarter 0 partials go to poX (separate region), quarters 1..3 to poB
// contiguously (j-1 indexed) — two-pointer select, no stride trickery.
__global__ __launch_bounds__(512, 2) void attn(const u16* __restrict__ qb,
        const u16* __restrict__ kb, const u16* __restrict__ vtb,
        u16* __restrict__ poX, u16* __restrict__ poB,
        float* __restrict__ pmB, float* __restrict__ plB) {
    __shared__ __align__(16) u16 Ks[6 * 64 * 32];
    __shared__ __align__(16) u16 Vs[2 * 192 * 32];
    int id = blockIdx.x;
    int bh = id & 31, rest = id >> 5;    // same-bh blocks share XCD (id%8 = bh%8)
    int t = rest & 3, j = rest >> 2;
    int tid = threadIdx.x, wave = tid >> 6, lane = tid & 63;
    int quad = lane >> 4, l16 = lane & 15;

    const size_t poElems = (size_t)256 * 256 * 192;
    const size_t mlElems = (size_t)256 * 256;
    u16* po = (j == 0) ? poX : (poB + (size_t)(j - 1) * poElems);
    float* pm = pmB + (size_t)j * mlElems;
    float* pl = plB + (size_t)j * mlElems;

    const u16* kbase0 = kb + (size_t)bh * L_ * DQ_;
    const u16* vbase0 = vtb + (size_t)bh * (size_t)DQ_ * L_;
    floatx4 zero4 = {0.f, 0.f, 0.f, 0.f};

    for (int seg = 0; seg < 2; ++seg) {
        const int QT = seg == 0 ? (7 - t) : t;
        const int st0 = j * (QT + 1);
        const int st1 = st0 + QT;

        bf16x8 aq[2][6];
        const u16* qbase = qb + ((size_t)bh * L_ + QT * 256 + wave * 16 + l16) * DQ_;
        for (int a = 0; a < 2; a++)
            for (int kk = 0; kk < 6; kk++)
                aq[a][kk] = *(const bf16x8*)(qbase + a * 128 * DQ_ + kk * 32 + quad * 8);

        floatx4 o[2][12];
        for (int a = 0; a < 2; a++) for (int i = 0; i < 12; i++) o[a][i] = zero4;
        float m_i[2] = {-INFINITY, -INFINITY};
        float l_i[2] = {0.f, 0.f};

        for (int st = st0; st <= st1; ++st) {
            const u16* kg = kbase0 + (size_t)st * 64 * DQ_;
            for (int it = 0; it < 3; ++it) {
                int c = it * 512 + tid;
                int kk = c >> 8, cc = c & 255;
                int s = cc >> 2, q4 = cc & 3;
                gld_lds16(kg + (size_t)s * DQ_ + kk * 32 + q4 * 8, Ks + c * 8);
            }
            const u16* vg = vbase0 + st * 64;
            for (int it = 0; it < 3; ++it) {
                int c = it * 512 + tid;
                int g = (c >= 768) ? 1 : 0;
                int cc = c - g * 768;
                int d = cc >> 2, q4 = cc & 3;
                gld_lds16(vg + (size_t)d * L_ + g * 32 + q4 * 8, Vs + c * 8);
            }
            __syncthreads();

            int R0 = QT * 256 + wave * 16 - st * 64;
            int R1 = R0 + 128;
            int smax0 = min(3, (R0 + 15) >> 4);
            int smax1 = min(3, (R1 + 15) >> 4);
            bool live0 = smax0 >= 0, live1 = smax1 >= 0;

            float pv[2][4][4];
            float mxa[2] = {-INFINITY, -INFINITY};
#pragma unroll
            for (int stile = 0; stile < 4; ++stile) {
                if (stile > smax1) {
                    for (int r = 0; r < 4; r++) { pv[0][stile][r] = 0.f; pv[1][stile][r] = 0.f; }
                    continue;
                }
                bool do0 = (stile <= smax0);
                floatx4 s1v = zero4, s0v = zero4;
                for (int kk = 0; kk < 6; kk++) {
                    bf16x8 kf = *(const bf16x8*)(Ks + kk * 2048 + (stile * 16 + l16) * 32 + quad * 8);
                    s1v = __builtin_amdgcn_mfma_f32_16x16x32_bf16(kf, aq[1][kk], s1v, 0, 0, 0);
                    if (do0) s0v = __builtin_amdgcn_mfma_f32_16x16x32_bf16(kf, aq[0][kk], s0v, 0, 0, 0);
                }
                int sb = stile * 16;
                if (sb + 15 > R1) {
                    for (int r = 0; r < 4; r++) {
                        float v = (sb + quad * 4 + r > R1 + l16) ? -1e30f : s1v[r];
                        pv[1][stile][r] = v; mxa[1] = fmaxf(mxa[1], v);
                    }
                } else {
                    for (int r = 0; r < 4; r++) { pv[1][stile][r] = s1v[r]; mxa[1] = fmaxf(mxa[1], s1v[r]); }
                }
                if (do0) {
                    if (sb + 15 > R0) {
                        for (int r = 0; r < 4; r++) {
                            float v = (sb + quad * 4 + r > R0 + l16) ? -1e30f : s0v[r];
                            pv[0][stile][r] = v; mxa[0] = fmaxf(mxa[0], v);
                        }
                    } else {
                        for (int r = 0; r < 4; r++) { pv[0][stile][r] = s0v[r]; mxa[0] = fmaxf(mxa[0], s0v[r]); }
                    }
                } else {
                    for (int r = 0; r < 4; r++) pv[0][stile][r] = 0.f;
                }
            }

            bf16x8 pf[2][2];
            bool lv[2] = {live0, live1};
            int smx[2] = {smax0, smax1};
#pragma unroll
            for (int a = 0; a < 2; a++) {
                if (!lv[a]) continue;
                float mx = mxa[a];
                mx = fmaxf(mx, __shfl_xor(mx, 16));
                mx = fmaxf(mx, __shfl_xor(mx, 32));
                float mn = fmaxf(m_i[a], mx);
                float alpha = exp2f(m_i[a] - mn);
                m_i[a] = mn;
                float rs = 0.f;
#pragma unroll
                for (int stile = 0; stile < 4; ++stile) {
                    if (stile > smx[a]) continue;
                    for (int r = 0; r < 4; r++) {
                        float e = exp2f(pv[a][stile][r] - mn);
                        pv[a][stile][r] = e;
                        rs += e;
                    }
                }
                rs += __shfl_xor(rs, 16);
                rs += __shfl_xor(rs, 32);
                l_i[a] = l_i[a] * alpha + rs;
                if (__any(alpha != 1.0f))
                    for (int i = 0; i < 12; i++) o[a][i] *= alpha;
                for (int g = 0; g < 2; g++) {
                    union { bf16x8 v; u16 s[8]; } u;
                    for (int r = 0; r < 4; r++) {
                        u.s[r]     = f2bf(pv[a][g * 2][r]);
                        u.s[4 + r] = f2bf(pv[a][g * 2 + 1][r]);
                    }
                    pf[a][g] = u.v;
                }
            }

            for (int g = 0; g < 2; g++)
                for (int dtile = 0; dtile < 12; dtile++) {
                    bf16x8 vf = *(const bf16x8*)(Vs + g * 6144 + (dtile * 16 + l16) * 32 + quad * 8);
                    if (live0)
                        o[0][dtile] = __builtin_amdgcn_mfma_f32_16x16x32_bf16(vf, pf[0][g], o[0][dtile], 0, 0, 0);
                    if (live1)
                        o[1][dtile] = __builtin_amdgcn_mfma_f32_16x16x32_bf16(vf, pf[1][g], o[1][dtile], 0, 0, 0);
                }
            __syncthreads();
        }

        int tile = bh * 8 + QT;
        for (int a = 0; a < 2; a++) {
            int q = a * 128 + wave * 16 + l16;
            u16* dst = po + ((size_t)tile * 256 + q) * 192;
            for (int dtile = 0; dtile < 12; dtile++) {
                ushort4 pk;
                pk.x = f2bf(o[a][dtile][0]);
                pk.y = f2bf(o[a][dtile][1]);
                pk.z = f2bf(o[a][dtile][2]);
                pk.w = f2bf(o[a][dtile][3]);
                *(ushort4*)(dst + dtile * 16 + quad * 4) = pk;
            }
            if (quad == 0) {
                pm[(size_t)tile * 256 + q] = m_i[a];
                pl[(size_t)tile * 256 + q] = l_i[a];
            }
        }
        __syncthreads();
    }
}

// ---------------- merge the four split-s quarters -> ao (B,L,H,192) bf16 ----------------
__global__ void attn_merge4(const u16* __restrict__ poX, const u16* __restrict__ poB,
                            const float* __restrict__ pmB, const float* __restrict__ plB,
                            u16* __restrict__ ao) {
    const size_t poElems = (size_t)256 * 256 * 192;
    const size_t mlElems = (size_t)256 * 256;
    int idx = blockIdx.x * blockDim.x + threadIdx.x;   // 256*256*48
    int c = idx % 48; int rest = idx / 48;
    int q = rest & 255; int tile = rest >> 8;
    int bh = tile >> 3, QT = tile & 7;
    size_t mi = (size_t)tile * 256 + q;
    float mv[4], lv[4];
    float m = -INFINITY;
    for (int jj = 0; jj < 4; jj++) {
        mv[jj] = pmB[jj * mlElems + mi];
        lv[jj] = plB[jj * mlElems + mi];
        m = fmaxf(m, mv[jj]);
    }
    float denom = 0.f, sc[4];
    for (int jj = 0; jj < 4; jj++) {
        sc[jj] = exp2f(mv[jj] - m);
        denom += lv[jj] * sc[jj];
    }
    float inv = 1.0f / denom;
    float acc[4] = {0.f, 0.f, 0.f, 0.f};
    for (int jj = 0; jj < 4; jj++) {
        float s = sc[jj] * inv;
        const u16* src = (jj == 0) ? (poX + mi * 192 + c * 4)
                                   : (poB + (size_t)(jj - 1) * poElems + mi * 192 + c * 4);
        ushort4 u = *(const ushort4*)src;
        acc[0] += bf2f(u.x) * s;
        acc[1] += bf2f(u.y) * s;
        acc[2] += bf2f(u.z) * s;
        acc[3] += bf2f(u.w) * s;
    }
    int b = bh >> 4, h = bh & 15;
    int l = QT * 256 + q;
    u16* dst = ao + (((size_t)(b * L_ + l)) * H_ + h) * DQ_ + c * 4;
    ushort4 pk;
    pk.x = f2bf(acc[0]);
    pk.y = f2bf(acc[1]);
    pk.z = f2bf(acc[2]);
    pk.w = f2bf(acc[3]);
    *(ushort4*)dst = pk;
}

extern "C" void kernel_launch(void* const* d_in, const int* in_sizes, int n_in,
                              void* d_out, int out_size, void* d_ws, size_t ws_size,
                              hipStream_t stream) {
    const float* x    = (const float*)d_in[0];
    const float* cosT = (const float*)d_in[1];
    const float* sinT = (const float*)d_in[2];
    const float* wq   = (const float*)d_in[3];
    const float* wkv  = (const float*)d_in[4];
    const float* wup  = (const float*)d_in[5];
    const float* wout = (const float*)d_in[6];
    float* out = (float*)d_out;
    char* ws = (char*)d_ws;

    size_t off = 0;
    auto alloc = [&](size_t b) { size_t r = off; off += (b + 255) & ~(size_t)255; return r; };
    u16* xb     = (u16*)(ws + alloc((size_t)M_ * E_ * 2));   // 16.78 MB, dead after gemm2
    u16* wqT    = (u16*)(ws + alloc((size_t)NQ_ * E_ * 2));  // 12.58 MB, dead after gemm1
    u16* wkvT   = (u16*)(ws + alloc((size_t)NKVP_ * E_ * 2));
    u16* wupT   = (u16*)(ws + alloc((size_t)NUP_ * RK_ * 2));
    u16* woutT  = (u16*)(ws + alloc((size_t)E_ * NQ_ * 2));  // LIVE until final gemm
    u16* qb     = (u16*)(ws + alloc((size_t)B_ * H_ * L_ * DQ_ * 2));
    u16* kb     = (u16*)(ws + alloc((size_t)B_ * H_ * L_ * DQ_ * 2));
    u16* vtb    = (u16*)(ws + alloc((size_t)B_ * H_ * DQ_ * L_ * 2));
    u16* ao     = (u16*)(ws + alloc((size_t)M_ * NQ_ * 2));  // LIVE (merge out)
    u16* ckv    = (u16*)(ws + alloc((size_t)M_ * RK_ * 2));
    u16* kropeb = (u16*)(ws + alloc((size_t)M_ * RD_ * 2));
    char* scratch = ws + alloc((size_t)M_ * NUP_ * 4);       // 83.9 MB union region
    float* q_all  = (float*)(scratch);                        // dead after build_q
    float* kv_lat = (float*)(scratch + (size_t)M_ * NQ_ * 4);
    float* up     = (float*)(scratch);                        // dead after build_kvt

    // attn partials: quarter 0 in dead xb+wqT region (25.17 <= 29.36 MB);
    // quarters 1..3 + pm/pl in scratch (75.50 + 2.10 = 77.6 <= 83.9 MB).
    size_t poSz = (size_t)256 * 256 * 192 * 2;               // 25.166 MB
    size_t mlSz = (size_t)256 * 256 * 4;                     // 0.262 MB
    u16*   poX = (u16*)(ws);                                 // quarter 0
    u16*   poB = (u16*)(scratch);                            // quarters 1..3
    float* pmA = (float*)(scratch + 3 * poSz);               // pm[j=0..3]
    float* plA = (float*)(scratch + 3 * poSz + 4 * mlSz);    // pl[j=0..3]

    dim3 tb(32, 8);
    int n4 = M_ * E_ / 4;
    convert_bf16<<<(n4 + 255) / 256, 256, 0, stream>>>(x, xb, n4);
    transpose_w<<<dim3(NQ_ / 32, E_ / 32), tb, 0, stream>>>(wq, wqT, E_, NQ_, NQ_);
    transpose_w<<<dim3(NKVP_ / 32, E_ / 32), tb, 0, stream>>>(wkv, wkvT, E_, NKV_, NKVP_);
    transpose_w<<<dim3(NUP_ / 32, RK_ / 32), tb, 0, stream>>>(wup, wupT, RK_, NUP_, NUP_);
    transpose_w<<<dim3(E_ / 32, NQ_ / 32), tb, 0, stream>>>(wout, woutT, NQ_, E_, E_);

    gemm_bt<<<dim3(NQ_ / 128, M_ / 128), 256, 0, stream>>>(xb, wqT, q_all, M_, NQ_, E_);
    gemm_bt<<<dim3(NKVP_ / 128, M_ / 128), 256, 0, stream>>>(xb, wkvT, kv_lat, M_, NKVP_, E_);

    int nq = M_ * H_ * 96;
    build_q<<<(nq + 255) / 256, 256, 0, stream>>>(q_all, cosT, sinT, qb);
    int nc = M_ * 288;
    build_ckv<<<(nc + 255) / 256, 256, 0, stream>>>(kv_lat, cosT, sinT, ckv, kropeb);

    gemm_bt<<<dim3(NUP_ / 128, M_ / 128), 256, 0, stream>>>(ckv, wupT, up, M_, NUP_, RK_);
    build_kvt<<<B_ * H_ * 32, 256, 0, stream>>>(up, kropeb, kb, vtb);

    attn<<<512, 512, 0, stream>>>(qb, kb, vtb, poX, poB, pmA, plA);
    attn_merge4<<<(256 * 256 * 48) / 256, 256, 0, stream>>>(poX, poB, pmA, plA, ao);

    gemm_bt<<<dim3(E_ / 128, M_ / 128), 256, 0, stream>>>(ao, woutT, out, M_, E_, NQ_);
}

// Round 6
// 620.402 us; speedup vs baseline: 1.0378x; 1.0378x over previous
//
#include <hip/hip_runtime.h>
#include <stdint.h>

#define H_ 16
#define DH_ 128
#define RK_ 512
#define RD_ 64
#define B_ 2
#define L_ 2048
#define E_ 2048
#define DQ_ 192            // DH+RD
#define NQ_ (H_*DQ_)       // 3072
#define NKV_ 576
#define NKVP_ 640
#define NUP_ (H_*(2*DH_+RD_)) // 5120
#define M_ (B_*L_)         // 4096

typedef unsigned short u16;
typedef __bf16 bf16x8 __attribute__((ext_vector_type(8)));
typedef float floatx4 __attribute__((ext_vector_type(4)));

__device__ __forceinline__ u16 f2bf(float f) {
    union { float f; uint32_t u; } v; v.f = f;
    uint32_t u = v.u;
    u = (u + 0x7fffu + ((u >> 16) & 1u)) >> 16;
    return (u16)u;
}
__device__ __forceinline__ float bf2f(u16 b) {
    union { uint32_t u; float f; } v; v.u = ((uint32_t)b) << 16; return v.f;
}

__device__ __forceinline__ void gld_lds16(const void* g, void* l) {
    __builtin_amdgcn_global_load_lds((__attribute__((address_space(1))) void*)(g),
                                     (__attribute__((address_space(3))) void*)(l),
                                     16, 0, 0);
}

// ---------------- fp32 -> bf16 elementwise (x) ----------------
__global__ void convert_bf16(const float* __restrict__ in, u16* __restrict__ out, int n4) {
    int i = blockIdx.x * blockDim.x + threadIdx.x;
    if (i >= n4) return;
    float4 v = ((const float4*)in)[i];
    uint2 o;
    o.x = (uint32_t)f2bf(v.x) | ((uint32_t)f2bf(v.y) << 16);
    o.y = (uint32_t)f2bf(v.z) | ((uint32_t)f2bf(v.w) << 16);
    ((uint2*)out)[i] = o;
}

// ---------------- W (KxN fp32) -> Wt (Npad x K bf16), zero pad ----------------
__global__ void transpose_w(const float* __restrict__ W, u16* __restrict__ Wt,
                            int K, int N, int Npad) {
    __shared__ float tile[32][33];
    int n0 = blockIdx.x * 32, k0 = blockIdx.y * 32;
    int tx = threadIdx.x, ty = threadIdx.y; // 32 x 8
    for (int i = 0; i < 4; i++) {
        int k = k0 + ty + i * 8, n = n0 + tx;
        tile[ty + i * 8][tx] = (n < N) ? W[(size_t)k * N + n] : 0.f;
    }
    __syncthreads();
    for (int i = 0; i < 4; i++) {
        int n = n0 + ty + i * 8, k = k0 + tx;
        Wt[(size_t)n * K + k] = f2bf(tile[tx][ty + i * 8]);
    }
}

// ---------------- GEMM: C(MxN fp32) = A(MxK bf16) * Bt(NxK bf16)^T ----------------
__global__ __launch_bounds__(256) void gemm_bt(const u16* __restrict__ A,
                                               const u16* __restrict__ Bt,
                                               float* __restrict__ C,
                                               int M, int N, int K) {
    __shared__ __align__(16) u16 As[128 * 32];
    __shared__ __align__(16) u16 Bs[128 * 32];
    const int tid = threadIdx.x;
    const int wave = tid >> 6, lane = tid & 63;
    const int quad = lane >> 4, l16 = lane & 15;
    const int m0 = blockIdx.y * 128, n0 = blockIdx.x * 128;
    const int wm = (wave >> 1) * 64, wn = (wave & 1) * 64;

    floatx4 zero4 = {0.f, 0.f, 0.f, 0.f};
    floatx4 acc[4][4];
    for (int i = 0; i < 4; i++) for (int j = 0; j < 4; j++) acc[i][j] = zero4;

    const u16* Ab = A + (size_t)m0 * K;
    const u16* Bb = Bt + (size_t)n0 * K;

    for (int k0 = 0; k0 < K; k0 += 32) {
        for (int it = 0; it < 2; ++it) {
            int c = it * 256 + tid;
            int row = c >> 2, cr = c & 3;
            gld_lds16(Ab + (size_t)row * K + k0 + cr * 8, As + c * 8);
            gld_lds16(Bb + (size_t)row * K + k0 + cr * 8, Bs + c * 8);
        }
        __syncthreads();
        bf16x8 af[4], bfr[4];
        for (int i = 0; i < 4; i++) af[i]  = *(const bf16x8*)(As + (wm + i * 16 + l16) * 32 + quad * 8);
        for (int j = 0; j < 4; j++) bfr[j] = *(const bf16x8*)(Bs + (wn + j * 16 + l16) * 32 + quad * 8);
        for (int i = 0; i < 4; i++)
            for (int j = 0; j < 4; j++)
                acc[i][j] = __builtin_amdgcn_mfma_f32_16x16x32_bf16(af[i], bfr[j], acc[i][j], 0, 0, 0);
        __syncthreads();
    }
    for (int i = 0; i < 4; i++)
        for (int j = 0; j < 4; j++) {
            int mrow = m0 + wm + i * 16 + quad * 4;
            int ncol = n0 + wn + j * 16 + l16;
            float* Cp = C + (size_t)mrow * N + ncol;
            for (int r = 0; r < 4; r++) Cp[(size_t)r * N] = acc[i][j][r];
        }
}

// ---------------- build q: rope + scale*log2e + layout (B,H,L,192) bf16 ----------------
__global__ void build_q(const float* __restrict__ q_all, const float* __restrict__ cosT,
                        const float* __restrict__ sinT, u16* __restrict__ qb) {
    const float QS = 0.07216878364870323f * 1.4426950408889634f; // 1/sqrt(192) * log2(e)
    int idx = blockIdx.x * blockDim.x + threadIdx.x;
    if (idx >= M_ * H_ * 96) return;
    int p = idx % 96; int t = idx / 96; int h = t % H_; int row = t / H_;
    int l = row & (L_ - 1); int b = row >> 11;
    const float* src = q_all + (size_t)row * NQ_ + h * DQ_;
    u16* dst = qb + ((size_t)(b * H_ + h) * L_ + l) * DQ_;
    int d = 2 * p;
    float x1 = src[d], x2 = src[d + 1];
    if (d < DH_) { dst[d] = f2bf(x1 * QS); dst[d + 1] = f2bf(x2 * QS); }
    else {
        int i = (d - DH_) >> 1;
        float c = cosT[(size_t)l * 32 + i], s = sinT[(size_t)l * 32 + i];
        dst[d]     = f2bf((x1 * c - x2 * s) * QS);
        dst[d + 1] = f2bf((x1 * s + x2 * c) * QS);
    }
}

// ---------------- build c_kv (bf16) + roped k_rope (bf16) ----------------
__global__ void build_ckv(const float* __restrict__ kv, const float* __restrict__ cosT,
                          const float* __restrict__ sinT, u16* __restrict__ ckv,
                          u16* __restrict__ kropeb) {
    int idx = blockIdx.x * blockDim.x + threadIdx.x;
    if (idx >= M_ * 288) return;
    int j = idx % 288; int row = idx / 288;
    int l = row & (L_ - 1);
    const float* src = kv + (size_t)row * NKVP_;
    if (j < 256) {
        ckv[(size_t)row * RK_ + 2 * j]     = f2bf(src[2 * j]);
        ckv[(size_t)row * RK_ + 2 * j + 1] = f2bf(src[2 * j + 1]);
    } else {
        int i = j - 256;
        float x1 = src[RK_ + 2 * i], x2 = src[RK_ + 2 * i + 1];
        float c = cosT[(size_t)l * 32 + i], s = sinT[(size_t)l * 32 + i];
        kropeb[(size_t)row * RD_ + 2 * i]     = f2bf(x1 * c - x2 * s);
        kropeb[(size_t)row * RD_ + 2 * i + 1] = f2bf(x1 * s + x2 * c);
    }
}

// ---------------- build k (B,H,L,192) + vT (B,H,192,L perm) bf16 ----------------
// vtb stores s-index permuted within each 32-group: k = ((s>>2)&3)*8 + ((s>>4)&1)*4 + (s&3)
// so the PV MFMA's B-frag element (k=quad*8+j) matches the S^T C-layout rows.
__global__ __launch_bounds__(256) void build_kvt(const float* __restrict__ up,
        const u16* __restrict__ kropeb, u16* __restrict__ kb, u16* __restrict__ vtb) {
    __shared__ float vt[64][193];
    int blk = blockIdx.x;          // (b*H+h)*32 + lt
    int lt = blk & 31; int bh = blk >> 5; int h = bh % H_; int b = bh / H_;
    int tid = threadIdx.x;
    int l0 = lt * 64;
    for (int it = 0; it < 48; ++it) {
        int idx = it * 256 + tid;  // 64*192
        int lr = idx / 192, d = idx % 192;
        size_t row = (size_t)b * L_ + l0 + lr;
        float vv = (d < DH_) ? up[row * NUP_ + h * 320 + DH_ + d]
                             : up[row * NUP_ + h * 320 + 2 * DH_ + (d - DH_)];
        vt[lr][d] = vv;
        u16 kbf = (d < DH_) ? f2bf(up[row * NUP_ + h * 320 + d])
                            : kropeb[row * RD_ + (d - DH_)];
        kb[((size_t)bh * L_ + l0 + lr) * DQ_ + d] = kbf;
    }
    __syncthreads();
    for (int it = 0; it < 48; ++it) {
        int idx = it * 256 + tid;
        int lr = idx & 63, d = idx >> 6;
        int l = l0 + lr;
        int s5 = l & 31;
        int k5 = ((s5 >> 2) & 3) * 8 + ((s5 >> 4) & 1) * 4 + (s5 & 3);
        int lp = (l & ~31) | k5;
        vtb[((size_t)bh * DQ_ + d) * L_ + lp] = f2bf(vt[lr][d]);
    }
}

// ---------------- flash attention, causal, S^T, 256-thread blocks ----------------
// Key fact (rounds 2-5): VGPR_Count excludes AGPRs. This body = 128 arch +
// 96 acc = 224/wave -> 2 waves/SIMD. A 4-wave block therefore leaves room for
// a SECOND 4-wave block on the CU (LDS 2x48=96KB<=160): two independent
// blocks overlap each other's barrier/DMA stalls.
// Q-tile 128 rows: wave w owns rows {a*64 + w*16 + l16 : a in 0,1}.
// Grid = 32bh x 8p x 2j = 512 blocks; block = half-j of QT=15-p then QT=p ->
// exactly 17 st-iters each. id%8=bh%8 keeps same-bh blocks on one XCD.
__global__ __launch_bounds__(256, 2) void attn(const u16* __restrict__ qb,
        const u16* __restrict__ kb, const u16* __restrict__ vtb,
        u16* __restrict__ poX, u16* __restrict__ poB,
        float* __restrict__ pmB, float* __restrict__ plB) {
    __shared__ __align__(16) u16 Ks[6 * 64 * 32];
    __shared__ __align__(16) u16 Vs[2 * 192 * 32];
    int id = blockIdx.x;
    int bh = id & 31, rest = id >> 5;
    int p = rest & 7, j = rest >> 3;
    int tid = threadIdx.x, wave = tid >> 6, lane = tid & 63;
    int quad = lane >> 4, l16 = lane & 15;

    const size_t mlElems = (size_t)512 * 128;
    u16* po = j ? poB : poX;
    float* pm = pmB + (size_t)j * mlElems;
    float* pl = plB + (size_t)j * mlElems;

    const u16* kbase0 = kb + (size_t)bh * L_ * DQ_;
    const u16* vbase0 = vtb + (size_t)bh * (size_t)DQ_ * L_;
    floatx4 zero4 = {0.f, 0.f, 0.f, 0.f};

    for (int seg = 0; seg < 2; ++seg) {
        const int QT = seg == 0 ? (15 - p) : p;   // 128-row q-tile index
        const int st0 = j * (QT + 1);
        const int st1 = st0 + QT;

        bf16x8 aq[2][6];
        const u16* qbase = qb + ((size_t)bh * L_ + QT * 128 + wave * 16 + l16) * DQ_;
        for (int a = 0; a < 2; a++)
            for (int kk = 0; kk < 6; kk++)
                aq[a][kk] = *(const bf16x8*)(qbase + a * 64 * DQ_ + kk * 32 + quad * 8);

        floatx4 o[2][12];
        for (int a = 0; a < 2; a++) for (int i = 0; i < 12; i++) o[a][i] = zero4;
        float m_i[2] = {-INFINITY, -INFINITY};
        float l_i[2] = {0.f, 0.f};

        for (int st = st0; st <= st1; ++st) {
            // stage K: Ks[kk6][64][32], 6 lds-dma per thread
            const u16* kg = kbase0 + (size_t)st * 64 * DQ_;
            for (int it = 0; it < 6; ++it) {
                int c = it * 256 + tid;
                int kk = c >> 8, cc = c & 255;
                int s = cc >> 2, q4 = cc & 3;
                gld_lds16(kg + (size_t)s * DQ_ + kk * 32 + q4 * 8, Ks + c * 8);
            }
            // stage V: Vs[g2][192][32]
            const u16* vg = vbase0 + st * 64;
            for (int it = 0; it < 6; ++it) {
                int c = it * 256 + tid;
                int g = (c >= 768) ? 1 : 0;
                int cc = c - g * 768;
                int d = cc >> 2, q4 = cc & 3;
                gld_lds16(vg + (size_t)d * L_ + g * 32 + q4 * 8, Vs + c * 8);
            }
            __syncthreads();

            // liveness: R multiples of 16; rowset live iff R >= 0
            int R0 = QT * 128 + wave * 16 - st * 64;
            int R1 = R0 + 64;
            int smax0 = min(3, (R0 + 15) >> 4);
            int smax1 = min(3, (R1 + 15) >> 4);
            bool live0 = smax0 >= 0, live1 = smax1 >= 0;

            float pv[2][4][4];
            float mxa[2] = {-INFINITY, -INFINITY};
#pragma unroll
            for (int stile = 0; stile < 4; ++stile) {
                if (stile > smax1) {
                    for (int r = 0; r < 4; r++) { pv[0][stile][r] = 0.f; pv[1][stile][r] = 0.f; }
                    continue;
                }
                bool do0 = (stile <= smax0);
                floatx4 s1v = zero4, s0v = zero4;
                for (int kk = 0; kk < 6; kk++) {
                    bf16x8 kf = *(const bf16x8*)(Ks + kk * 2048 + (stile * 16 + l16) * 32 + quad * 8);
                    s1v = __builtin_amdgcn_mfma_f32_16x16x32_bf16(kf, aq[1][kk], s1v, 0, 0, 0);
                    if (do0) s0v = __builtin_amdgcn_mfma_f32_16x16x32_bf16(kf, aq[0][kk], s0v, 0, 0, 0);
                }
                int sb = stile * 16;
                if (sb + 15 > R1) {
                    for (int r = 0; r < 4; r++) {
                        float v = (sb + quad * 4 + r > R1 + l16) ? -1e30f : s1v[r];
                        pv[1][stile][r] = v; mxa[1] = fmaxf(mxa[1], v);
                    }
                } else {
                    for (int r = 0; r < 4; r++) { pv[1][stile][r] = s1v[r]; mxa[1] = fmaxf(mxa[1], s1v[r]); }
                }
                if (do0) {
                    if (sb + 15 > R0) {
                        for (int r = 0; r < 4; r++) {
                            float v = (sb + quad * 4 + r > R0 + l16) ? -1e30f : s0v[r];
                            pv[0][stile][r] = v; mxa[0] = fmaxf(mxa[0], v);
                        }
                    } else {
                        for (int r = 0; r < 4; r++) { pv[0][stile][r] = s0v[r]; mxa[0] = fmaxf(mxa[0], s0v[r]); }
                    }
                } else {
                    for (int r = 0; r < 4; r++) pv[0][stile][r] = 0.f;
                }
            }

            bf16x8 pf[2][2];
            bool lv[2] = {live0, live1};
            int smx[2] = {smax0, smax1};
#pragma unroll
            for (int a = 0; a < 2; a++) {
                if (!lv[a]) continue;
                float mx = mxa[a];
                mx = fmaxf(mx, __shfl_xor(mx, 16));
                mx = fmaxf(mx, __shfl_xor(mx, 32));
                float mn = fmaxf(m_i[a], mx);
                float alpha = exp2f(m_i[a] - mn);
                m_i[a] = mn;
                float rs = 0.f;
#pragma unroll
                for (int stile = 0; stile < 4; ++stile) {
                    if (stile > smx[a]) continue;
                    for (int r = 0; r < 4; r++) {
                        float e = exp2f(pv[a][stile][r] - mn);
                        pv[a][stile][r] = e;
                        rs += e;
                    }
                }
                rs += __shfl_xor(rs, 16);
                rs += __shfl_xor(rs, 32);
                l_i[a] = l_i[a] * alpha + rs;
                if (__any(alpha != 1.0f))
                    for (int i = 0; i < 12; i++) o[a][i] *= alpha;
                for (int g = 0; g < 2; g++) {
                    union { bf16x8 v; u16 s[8]; } u;
                    for (int r = 0; r < 4; r++) {
                        u.s[r]     = f2bf(pv[a][g * 2][r]);
                        u.s[4 + r] = f2bf(pv[a][g * 2 + 1][r]);
                    }
                    pf[a][g] = u.v;
                }
            }

            for (int g = 0; g < 2; g++)
                for (int dtile = 0; dtile < 12; dtile++) {
                    bf16x8 vf = *(const bf16x8*)(Vs + g * 6144 + (dtile * 16 + l16) * 32 + quad * 8);
                    if (live0)
                        o[0][dtile] = __builtin_amdgcn_mfma_f32_16x16x32_bf16(vf, pf[0][g], o[0][dtile], 0, 0, 0);
                    if (live1)
                        o[1][dtile] = __builtin_amdgcn_mfma_f32_16x16x32_bf16(vf, pf[1][g], o[1][dtile], 0, 0, 0);
                }
            __syncthreads();
        }

        // write partials: po[tile][q 128][d 192] bf16, pm/pl[tile][q 128]
        int tile = bh * 16 + QT;
        for (int a = 0; a < 2; a++) {
            int q = a * 64 + wave * 16 + l16;
            u16* dst = po + ((size_t)tile * 128 + q) * 192;
            for (int dtile = 0; dtile < 12; dtile++) {
                ushort4 pk;
                pk.x = f2bf(o[a][dtile][0]);
                pk.y = f2bf(o[a][dtile][1]);
                pk.z = f2bf(o[a][dtile][2]);
                pk.w = f2bf(o[a][dtile][3]);
                *(ushort4*)(dst + dtile * 16 + quad * 4) = pk;
            }
            if (quad == 0) {
                pm[(size_t)tile * 128 + q] = m_i[a];
                pl[(size_t)tile * 128 + q] = l_i[a];
            }
        }
        __syncthreads();
    }
}

// ---------------- merge the two split-s halves -> ao (B,L,H,192) bf16 ----------------
__global__ void attn_merge2(const u16* __restrict__ poX, const u16* __restrict__ poB,
                            const float* __restrict__ pmB, const float* __restrict__ plB,
                            u16* __restrict__ ao) {
    const size_t mlElems = (size_t)512 * 128;
    int idx = blockIdx.x * blockDim.x + threadIdx.x;   // 512*128*48
    int c = idx % 48; int rest = idx / 48;
    int q = rest & 127; int tile = rest >> 7;
    int bh = tile >> 4, QT = tile & 15;
    size_t mi = (size_t)tile * 128 + q;
    float m0 = pmB[mi], m1 = pmB[mlElems + mi];
    float l0 = plB[mi], l1 = plB[mlElems + mi];
    float m = fmaxf(m0, m1);
    float a0 = exp2f(m0 - m), a1 = exp2f(m1 - m);
    float inv = 1.0f / (l0 * a0 + l1 * a1);
    float s0 = a0 * inv, s1 = a1 * inv;
    ushort4 u0 = *(const ushort4*)(poX + mi * 192 + c * 4);
    ushort4 u1 = *(const ushort4*)(poB + mi * 192 + c * 4);
    int b = bh >> 4, h = bh & 15;
    int l = QT * 128 + q;
    u16* dst = ao + (((size_t)(b * L_ + l)) * H_ + h) * DQ_ + c * 4;
    ushort4 pk;
    pk.x = f2bf(bf2f(u0.x) * s0 + bf2f(u1.x) * s1);
    pk.y = f2bf(bf2f(u0.y) * s0 + bf2f(u1.y) * s1);
    pk.z = f2bf(bf2f(u0.z) * s0 + bf2f(u1.z) * s1);
    pk.w = f2bf(bf2f(u0.w) * s0 + bf2f(u1.w) * s1);
    *(ushort4*)dst = pk;
}

extern "C" void kernel_launch(void* const* d_in, const int* in_sizes, int n_in,
                              void* d_out, int out_size, void* d_ws, size_t ws_size,
                              hipStream_t stream) {
    const float* x    = (const float*)d_in[0];
    const float* cosT = (const float*)d_in[1];
    const float* sinT = (const float*)d_in[2];
    const float* wq   = (const float*)d_in[3];
    const float* wkv  = (const float*)d_in[4];
    const float* wup  = (const float*)d_in[5];
    const float* wout = (const float*)d_in[6];
    float* out = (float*)d_out;
    char* ws = (char*)d_ws;

    size_t off = 0;
    auto alloc = [&](size_t b) { size_t r = off; off += (b + 255) & ~(size_t)255; return r; };
    u16* xb     = (u16*)(ws + alloc((size_t)M_ * E_ * 2));   // 16.78 MB, dead after gemm2
    u16* wqT    = (u16*)(ws + alloc((size_t)NQ_ * E_ * 2));  // 12.58 MB, dead after gemm1
    u16* wkvT   = (u16*)(ws + alloc((size_t)NKVP_ * E_ * 2));
    u16* wupT   = (u16*)(ws + alloc((size_t)NUP_ * RK_ * 2));
    u16* woutT  = (u16*)(ws + alloc((size_t)E_ * NQ_ * 2));  // LIVE until final gemm
    u16* qb     = (u16*)(ws + alloc((size_t)B_ * H_ * L_ * DQ_ * 2));
    u16* kb     = (u16*)(ws + alloc((size_t)B_ * H_ * L_ * DQ_ * 2));
    u16* vtb    = (u16*)(ws + alloc((size_t)B_ * H_ * DQ_ * L_ * 2));
    u16* ao     = (u16*)(ws + alloc((size_t)M_ * NQ_ * 2));  // LIVE (merge out)
    u16* ckv    = (u16*)(ws + alloc((size_t)M_ * RK_ * 2));
    u16* kropeb = (u16*)(ws + alloc((size_t)M_ * RD_ * 2));
    char* scratch = ws + alloc((size_t)M_ * NUP_ * 4);       // 83.9 MB union region
    float* q_all  = (float*)(scratch);                        // dead after build_q
    float* kv_lat = (float*)(scratch + (size_t)M_ * NQ_ * 4);
    float* up     = (float*)(scratch);                        // dead after build_kvt

    // attn partials: half 0 in dead xb+wqT region (25.17 <= 29.36 MB);
    // half 1 + pm/pl in scratch (25.17 + 1.05 = 26.2 <= 83.9 MB).
    size_t poSz = (size_t)512 * 128 * 192 * 2;               // 25.166 MB (512 tiles x 128 q x 192 d)
    size_t mlSz = (size_t)512 * 128 * 4;                     // 0.262 MB
    u16*   poX = (u16*)(ws);                                 // half 0
    u16*   poB = (u16*)(scratch);                            // half 1
    float* pmA = (float*)(scratch + poSz);                   // pm[j=0..1]
    float* plA = (float*)(scratch + poSz + 2 * mlSz);        // pl[j=0..1]

    dim3 tb(32, 8);
    int n4 = M_ * E_ / 4;
    convert_bf16<<<(n4 + 255) / 256, 256, 0, stream>>>(x, xb, n4);
    transpose_w<<<dim3(NQ_ / 32, E_ / 32), tb, 0, stream>>>(wq, wqT, E_, NQ_, NQ_);
    transpose_w<<<dim3(NKVP_ / 32, E_ / 32), tb, 0, stream>>>(wkv, wkvT, E_, NKV_, NKVP_);
    transpose_w<<<dim3(NUP_ / 32, RK_ / 32), tb, 0, stream>>>(wup, wupT, RK_, NUP_, NUP_);
    transpose_w<<<dim3(E_ / 32, NQ_ / 32), tb, 0, stream>>>(wout, woutT, NQ_, E_, E_);

    gemm_bt<<<dim3(NQ_ / 128, M_ / 128), 256, 0, stream>>>(xb, wqT, q_all, M_, NQ_, E_);
    gemm_bt<<<dim3(NKVP_ / 128, M_ / 128), 256, 0, stream>>>(xb, wkvT, kv_lat, M_, NKVP_, E_);

    int nq = M_ * H_ * 96;
    build_q<<<(nq + 255) / 256, 256, 0, stream>>>(q_all, cosT, sinT, qb);
    int nc = M_ * 288;
    build_ckv<<<(nc + 255) / 256, 256, 0, stream>>>(kv_lat, cosT, sinT, ckv, kropeb);

    gemm_bt<<<dim3(NUP_ / 128, M_ / 128), 256, 0, stream>>>(ckv, wupT, up, M_, NUP_, RK_);
    build_kvt<<<B_ * H_ * 32, 256, 0, stream>>>(up, kropeb, kb, vtb);

    attn<<<512, 256, 0, stream>>>(qb, kb, vtb, poX, poB, pmA, plA);
    attn_merge2<<<(512 * 128 * 48) / 256, 256, 0, stream>>>(poX, poB, pmA, plA, ao);

    gemm_bt<<<dim3(E_ / 128, M_ / 128), 256, 0, stream>>>(ao, woutT, out, M_, E_, NQ_);
}